// Round 1
// baseline (1305.967 us; speedup 1.0000x reference)
//
#include <hip/hip_runtime.h>
#include <math.h>

#define NOSC 2048
#define NB 16
#define DT 0.1f

// R layout: [32][NOSC]  rows 0..15 = sin(theta[b][:]), rows 16..31 = cos(theta[b][:])

__global__ void copy_theta_kernel(const float* __restrict__ th_in,
                                  float* __restrict__ th_out) {
    int idx = blockIdx.x * blockDim.x + threadIdx.x;
    if (idx < NB * NOSC) th_out[idx] = th_in[idx];
}

__global__ void sincos_kernel(const float* __restrict__ th,
                              float* __restrict__ R) {
    int idx = blockIdx.x * blockDim.x + threadIdx.x;  // = b*NOSC + j
    if (idx < NB * NOSC) {
        int b = idx >> 11;           // NOSC = 2048
        int j = idx & (NOSC - 1);
        float s, c;
        sincosf(th[idx], &s, &c);
        R[b * NOSC + j] = s;          // sin row (col b)
        R[(NB + b) * NOSC + j] = c;   // cos row (col 16+b)
    }
}

// grid = NOSC/16 = 128 blocks, block = 256 threads.
// thread (cg = t&15, rg = t>>4): row i = blk*16+rg, batch b = cg.
// Accumulates dotS = sum_j K[i,j]*sin(th[b,j]) and dotC likewise, then
// updates theta[b,i] in place (each (b,i) owned by exactly one thread).
__global__ void couple_kernel(const float* __restrict__ Kmat,
                              const float* __restrict__ Rm,
                              const float* __restrict__ omega,
                              const float* __restrict__ kg,
                              const float* __restrict__ mod,
                              float* __restrict__ th) {
    const int t = threadIdx.x;
    const int cg = t & 15;
    const int rg = t >> 4;
    const int i = blockIdx.x * 16 + rg;

    const float* __restrict__ Krow = Kmat + (size_t)i * NOSC;
    const float* __restrict__ Rs = Rm + (size_t)cg * NOSC;
    const float* __restrict__ Rc = Rm + (size_t)(NB + cg) * NOSC;

    float aS = 0.0f, aC = 0.0f;

#pragma unroll 4
    for (int j = 0; j < NOSC; j += 4) {
        float4 kv = *reinterpret_cast<const float4*>(Krow + j);
        float4 sv = *reinterpret_cast<const float4*>(Rs + j);
        float4 cv = *reinterpret_cast<const float4*>(Rc + j);
        aS = fmaf(kv.x, sv.x, aS);
        aS = fmaf(kv.y, sv.y, aS);
        aS = fmaf(kv.z, sv.z, aS);
        aS = fmaf(kv.w, sv.w, aS);
        aC = fmaf(kv.x, cv.x, aC);
        aC = fmaf(kv.y, cv.y, aC);
        aC = fmaf(kv.z, cv.z, aC);
        aC = fmaf(kv.w, cv.w, aC);
    }

    // coupling_sum = cos_i * dotS - sin_i * dotC, scaled by kg*(1+mod)/N
    const float sin_i = Rs[i];
    const float cos_i = Rc[i];
    const float scale = kg[0] * (1.0f + mod[0]) / (float)NOSC;
    const float coupling = cos_i * aS - sin_i * aC;

    float nt = th[(size_t)cg * NOSC + i] + DT * (omega[i] + scale * coupling);
    // wrap to (-pi, pi] exactly like the reference: atan2(sin, cos)
    float ws, wc;
    sincosf(nt, &ws, &wc);
    th[(size_t)cg * NOSC + i] = atan2f(ws, wc);
}

__global__ void coherence_kernel(const float* __restrict__ th,
                                 float* __restrict__ coh) {
    const int b = blockIdx.x;
    const int t = threadIdx.x;
    float sc = 0.0f, ss = 0.0f;
    for (int j = t; j < NOSC; j += 256) {
        float s, c;
        sincosf(th[(size_t)b * NOSC + j], &s, &c);
        sc += c;
        ss += s;
    }
    // wave (64-lane) reduction
    for (int off = 32; off > 0; off >>= 1) {
        sc += __shfl_down(sc, off);
        ss += __shfl_down(ss, off);
    }
    __shared__ float red[8];
    const int w = t >> 6;
    if ((t & 63) == 0) { red[w * 2] = sc; red[w * 2 + 1] = ss; }
    __syncthreads();
    if (t == 0) {
        float tc = 0.0f, ts = 0.0f;
        for (int k = 0; k < 4; ++k) { tc += red[k * 2]; ts += red[k * 2 + 1]; }
        tc /= (float)NOSC;
        ts /= (float)NOSC;
        coh[b] = sqrtf(tc * tc + ts * ts);
    }
}

extern "C" void kernel_launch(void* const* d_in, const int* in_sizes, int n_in,
                              void* d_out, int out_size, void* d_ws, size_t ws_size,
                              hipStream_t stream) {
    const float* theta_in = (const float*)d_in[0];
    const float* Kmat     = (const float*)d_in[1];
    const float* omega    = (const float*)d_in[2];
    const float* kg       = (const float*)d_in[3];
    const float* mod      = (const float*)d_in[4];

    float* th  = (float*)d_out;                // [NB][NOSC], final theta
    float* coh = (float*)d_out + NB * NOSC;    // [NB]
    float* R   = (float*)d_ws;                 // [32][NOSC] sin/cos workspace

    copy_theta_kernel<<<(NB * NOSC + 255) / 256, 256, 0, stream>>>(theta_in, th);

    for (int s = 0; s < 10; ++s) {
        sincos_kernel<<<(NB * NOSC + 255) / 256, 256, 0, stream>>>(th, R);
        couple_kernel<<<NOSC / 16, 256, 0, stream>>>(Kmat, R, omega, kg, mod, th);
    }

    coherence_kernel<<<NB, 256, 0, stream>>>(th, coh);
}

// Round 2
// 696.340 us; speedup vs baseline: 1.8755x; 1.8755x over previous
//
#include <hip/hip_runtime.h>
#include <math.h>

#define NOSC 2048
#define NB 16
#define DT 0.1f
#define M_TOT (NB * NOSC)   // 32768 outputs per step

// Workspace layout:
//   R: [32][NOSC] floats  rows 0..15 = sin(theta[b][:]), rows 16..31 = cos
//   P: [2*SPLIT][M_TOT] floats  partial dotS (first SPLIT rows) then dotC

// ---------- init: copy theta and build R ----------
__global__ void init_kernel(const float* __restrict__ th_in,
                            float* __restrict__ th,
                            float* __restrict__ R) {
    int o = blockIdx.x * blockDim.x + threadIdx.x;   // o = b*NOSC + j
    if (o < M_TOT) {
        float v = th_in[o];
        th[o] = v;
        float s, c;
        sincosf(v, &s, &c);
        R[o] = s;              // sin block
        R[M_TOT + o] = c;      // cos block  ((NB+b)*NOSC + j == M_TOT + o)
    }
}

// ---------- partial coupling sums (j-split GEMM) ----------
// grid = (NOSC/16, SPLIT), block = 256.
// thread: cg = t&15 (batch), rg = t>>4 (row in 16-row tile), i = bx*16+rg.
// Accumulates over j in [s*JT, (s+1)*JT). Output o = i*16+cg (coalesced store).
template <int SPLIT>
__global__ void couple_part_kernel(const float* __restrict__ Kmat,
                                   const float* __restrict__ Rm,
                                   float* __restrict__ P) {
    constexpr int JT = NOSC / SPLIT;
    const int t = threadIdx.x;
    const int cg = t & 15;
    const int rg = t >> 4;
    const int i = blockIdx.x * 16 + rg;
    const int s = blockIdx.y;
    const int jb = s * JT;

    const float* __restrict__ Krow = Kmat + (size_t)i * NOSC + jb;
    const float* __restrict__ Rs   = Rm + (size_t)cg * NOSC + jb;
    const float* __restrict__ Rc   = Rm + (size_t)(NB + cg) * NOSC + jb;

    float aS = 0.0f, aC = 0.0f;
#pragma unroll 4
    for (int j = 0; j < JT; j += 4) {
        float4 kv = *reinterpret_cast<const float4*>(Krow + j);
        float4 sv = *reinterpret_cast<const float4*>(Rs + j);
        float4 cv = *reinterpret_cast<const float4*>(Rc + j);
        aS = fmaf(kv.x, sv.x, aS);
        aS = fmaf(kv.y, sv.y, aS);
        aS = fmaf(kv.z, sv.z, aS);
        aS = fmaf(kv.w, sv.w, aS);
        aC = fmaf(kv.x, cv.x, aC);
        aC = fmaf(kv.y, cv.y, aC);
        aC = fmaf(kv.z, cv.z, aC);
        aC = fmaf(kv.w, cv.w, aC);
    }

    const int o = i * NB + cg;
    P[(size_t)s * M_TOT + o] = aS;
    P[(size_t)(SPLIT + s) * M_TOT + o] = aC;
}

// ---------- reduce partials, update theta, refresh R ----------
__global__ void update_kernel(const float* __restrict__ P, int split,
                              const float* __restrict__ omega,
                              const float* __restrict__ kg,
                              const float* __restrict__ mod,
                              float* __restrict__ th,
                              float* __restrict__ R) {
    const int o = blockIdx.x * blockDim.x + threadIdx.x;  // o = i*16 + b
    if (o >= M_TOT) return;
    const int i = o >> 4;
    const int b = o & 15;

    float aS = 0.0f, aC = 0.0f;
    for (int s = 0; s < split; ++s) {
        aS += P[(size_t)s * M_TOT + o];
        aC += P[(size_t)(split + s) * M_TOT + o];
    }

    const size_t ti = (size_t)b * NOSC + i;
    const float sin_i = R[ti];
    const float cos_i = R[M_TOT + ti];
    const float scale = kg[0] * (1.0f + mod[0]) * (1.0f / (float)NOSC);
    const float coupling = cos_i * aS - sin_i * aC;

    float nt = th[ti] + DT * (omega[i] + scale * coupling);
    float ws, wc;
    sincosf(nt, &ws, &wc);
    th[ti] = atan2f(ws, wc);   // wrap to (-pi, pi] exactly like reference
    R[ti] = ws;                // sin(wrapped) == sin(nt)
    R[M_TOT + ti] = wc;
}

// ---------- coherence from R (sin/cos of final theta already there) ----------
__global__ void coherence_kernel(const float* __restrict__ R,
                                 float* __restrict__ coh) {
    const int b = blockIdx.x;
    const int t = threadIdx.x;
    float ss = 0.0f, sc = 0.0f;
    for (int j = t; j < NOSC; j += 256) {
        ss += R[(size_t)b * NOSC + j];
        sc += R[M_TOT + (size_t)b * NOSC + j];
    }
    for (int off = 32; off > 0; off >>= 1) {
        ss += __shfl_down(ss, off);
        sc += __shfl_down(sc, off);
    }
    __shared__ float red[8];
    const int w = t >> 6;
    if ((t & 63) == 0) { red[w * 2] = sc; red[w * 2 + 1] = ss; }
    __syncthreads();
    if (t == 0) {
        float tc = 0.0f, ts = 0.0f;
        for (int k = 0; k < 4; ++k) { tc += red[k * 2]; ts += red[k * 2 + 1]; }
        tc /= (float)NOSC;
        ts /= (float)NOSC;
        coh[b] = sqrtf(tc * tc + ts * ts);
    }
}

// ---------- legacy fallback (round-1 path) for tiny workspaces ----------
__global__ void sincos_kernel(const float* __restrict__ th,
                              float* __restrict__ R) {
    int o = blockIdx.x * blockDim.x + threadIdx.x;
    if (o < M_TOT) {
        float s, c;
        sincosf(th[o], &s, &c);
        R[o] = s;
        R[M_TOT + o] = c;
    }
}

__global__ void couple_legacy_kernel(const float* __restrict__ Kmat,
                                     const float* __restrict__ Rm,
                                     const float* __restrict__ omega,
                                     const float* __restrict__ kg,
                                     const float* __restrict__ mod,
                                     float* __restrict__ th) {
    const int t = threadIdx.x;
    const int cg = t & 15;
    const int rg = t >> 4;
    const int i = blockIdx.x * 16 + rg;

    const float* __restrict__ Krow = Kmat + (size_t)i * NOSC;
    const float* __restrict__ Rs = Rm + (size_t)cg * NOSC;
    const float* __restrict__ Rc = Rm + (size_t)(NB + cg) * NOSC;

    float aS = 0.0f, aC = 0.0f;
#pragma unroll 4
    for (int j = 0; j < NOSC; j += 4) {
        float4 kv = *reinterpret_cast<const float4*>(Krow + j);
        float4 sv = *reinterpret_cast<const float4*>(Rs + j);
        float4 cv = *reinterpret_cast<const float4*>(Rc + j);
        aS = fmaf(kv.x, sv.x, aS);
        aS = fmaf(kv.y, sv.y, aS);
        aS = fmaf(kv.z, sv.z, aS);
        aS = fmaf(kv.w, sv.w, aS);
        aC = fmaf(kv.x, cv.x, aC);
        aC = fmaf(kv.y, cv.y, aC);
        aC = fmaf(kv.z, cv.z, aC);
        aC = fmaf(kv.w, cv.w, aC);
    }

    const float sin_i = Rs[i];
    const float cos_i = Rc[i];
    const float scale = kg[0] * (1.0f + mod[0]) / (float)NOSC;
    const float coupling = cos_i * aS - sin_i * aC;

    float nt = th[(size_t)cg * NOSC + i] + DT * (omega[i] + scale * coupling);
    float ws, wc;
    sincosf(nt, &ws, &wc);
    th[(size_t)cg * NOSC + i] = atan2f(ws, wc);
}

extern "C" void kernel_launch(void* const* d_in, const int* in_sizes, int n_in,
                              void* d_out, int out_size, void* d_ws, size_t ws_size,
                              hipStream_t stream) {
    const float* theta_in = (const float*)d_in[0];
    const float* Kmat     = (const float*)d_in[1];
    const float* omega    = (const float*)d_in[2];
    const float* kg       = (const float*)d_in[3];
    const float* mod      = (const float*)d_in[4];

    float* th  = (float*)d_out;               // [NB][NOSC] final theta
    float* coh = (float*)d_out + M_TOT;       // [NB]
    float* R   = (float*)d_ws;                // [2*M_TOT] sin/cos
    float* P   = (float*)d_ws + 2 * M_TOT;    // partials

    const size_t r_bytes = (size_t)2 * M_TOT * sizeof(float);
    auto p_bytes = [](int split) { return (size_t)2 * split * M_TOT * sizeof(float); };

    int split = 0;
    if (ws_size >= r_bytes + p_bytes(8)) split = 8;
    else if (ws_size >= r_bytes + p_bytes(4)) split = 4;
    else if (ws_size >= r_bytes + p_bytes(2)) split = 2;
    else if (ws_size >= r_bytes + p_bytes(1)) split = 1;

    init_kernel<<<(M_TOT + 255) / 256, 256, 0, stream>>>(theta_in, th, R);

    if (split > 0) {
        for (int s = 0; s < 10; ++s) {
            dim3 grid(NOSC / 16, split);
            if (split == 8)
                couple_part_kernel<8><<<grid, 256, 0, stream>>>(Kmat, R, P);
            else if (split == 4)
                couple_part_kernel<4><<<grid, 256, 0, stream>>>(Kmat, R, P);
            else if (split == 2)
                couple_part_kernel<2><<<grid, 256, 0, stream>>>(Kmat, R, P);
            else
                couple_part_kernel<1><<<grid, 256, 0, stream>>>(Kmat, R, P);
            update_kernel<<<(M_TOT + 255) / 256, 256, 0, stream>>>(P, split, omega, kg, mod, th, R);
        }
    } else {
        // tiny workspace fallback: legacy monolithic step
        for (int s = 0; s < 10; ++s) {
            sincos_kernel<<<(M_TOT + 255) / 256, 256, 0, stream>>>(th, R);
            couple_legacy_kernel<<<NOSC / 16, 256, 0, stream>>>(Kmat, R, omega, kg, mod, th);
        }
        sincos_kernel<<<(M_TOT + 255) / 256, 256, 0, stream>>>(th, R);
    }

    coherence_kernel<<<NB, 256, 0, stream>>>(R, coh);
}

// Round 3
// 177.715 us; speedup vs baseline: 7.3486x; 3.9183x over previous
//
#include <hip/hip_runtime.h>
#include <math.h>

#define NOSC 2048
#define NB 16
#define DT 0.1f
#define M_TOT (NB * NOSC)   // 32768

// New-path workspace layout:
//   R: [32][NOSC]  rows 0..15 = sin(theta[b][:]), rows 16..31 = cos
//   P: [32][NSPLIT][NOSC]  P[c][s][i] = partial dot over j-chunk s
#define NSPLIT 32
#define JR (NOSC / NSPLIT)   // 64

// ---------- init: copy theta and build R ----------
__global__ void init_kernel(const float* __restrict__ th_in,
                            float* __restrict__ th,
                            float* __restrict__ R) {
    int o = blockIdx.x * blockDim.x + threadIdx.x;   // o = b*NOSC + j
    if (o < M_TOT) {
        float v = th_in[o];
        th[o] = v;
        float s, c;
        sincosf(v, &s, &c);
        R[o] = s;
        R[M_TOT + o] = c;
    }
}

// ---------- transposed GEMM: C[c][i] = sum_j R[c][j] * K[j][i]  (K symmetric)
// grid = (NSPLIT, 16): bx = j-split s (XCD = s%8 keeps K slice L2-resident),
// by: ih = by&7 (i-tile of 256), half = by>>3 (0=sin cols, 1=cos cols).
// Lanes sweep i (coalesced K loads); R[c][j] wave-uniform -> scalar loads.
__global__ void gemm_kernel(const float* __restrict__ Kmat,
                            const float* __restrict__ Rm,
                            float* __restrict__ P) {
    const int t = threadIdx.x;
    const int s = blockIdx.x;
    const int ih = blockIdx.y & 7;
    const int half = blockIdx.y >> 3;
    const int i = ih * 256 + t;
    const int jb = s * JR;

    const float* __restrict__ Rbase = Rm + (size_t)(half * NB) * NOSC + jb;
    const float* __restrict__ Kp = Kmat + (size_t)jb * NOSC + i;

    float acc[16];
#pragma unroll
    for (int c = 0; c < 16; ++c) acc[c] = 0.0f;

#pragma unroll 4
    for (int jj = 0; jj < JR; ++jj) {
        const float kv = Kp[(size_t)jj * NOSC];
#pragma unroll
        for (int c = 0; c < 16; ++c)
            acc[c] = fmaf(Rbase[(size_t)c * NOSC + jj], kv, acc[c]);
    }

    float* __restrict__ Pp = P + ((size_t)(half * NB) * NSPLIT + s) * NOSC + i;
#pragma unroll
    for (int c = 0; c < 16; ++c)
        Pp[(size_t)c * NSPLIT * NOSC] = acc[c];
}

// ---------- reduce partials, update theta, refresh R ----------
// grid = M_TOT/64 blocks of 64: o = b*NOSC + i, lanes contiguous in i.
template <bool FINAL>
__global__ void update2_kernel(const float* __restrict__ P,
                               const float* __restrict__ omega,
                               const float* __restrict__ kg,
                               const float* __restrict__ mod,
                               float* __restrict__ th,
                               float* __restrict__ R) {
    const int o = blockIdx.x * 64 + threadIdx.x;
    const int b = o >> 11;           // NOSC = 2048
    const int i = o & (NOSC - 1);

    float aS = 0.0f, aC = 0.0f;
#pragma unroll 8
    for (int s = 0; s < NSPLIT; ++s) {
        aS += P[((size_t)b * NSPLIT + s) * NOSC + i];
        aC += P[((size_t)(NB + b) * NSPLIT + s) * NOSC + i];
    }

    const float sin_i = R[o];
    const float cos_i = R[M_TOT + o];
    const float scale = kg[0] * (1.0f + mod[0]) * (1.0f / (float)NOSC);
    const float coupling = cos_i * aS - sin_i * aC;

    float nt = th[o] + DT * (omega[i] + scale * coupling);
    float ws, wc;
    sincosf(nt, &ws, &wc);
    // wrap changes theta by 2*pi*k only -> sin/cos unchanged; defer atan2 to final step
    th[o] = FINAL ? atan2f(ws, wc) : nt;
    R[o] = ws;
    R[M_TOT + o] = wc;
}

// ---------- coherence from R ----------
__global__ void coherence_kernel(const float* __restrict__ R,
                                 float* __restrict__ coh) {
    const int b = blockIdx.x;
    const int t = threadIdx.x;
    float ss = 0.0f, sc = 0.0f;
    for (int j = t; j < NOSC; j += 256) {
        ss += R[(size_t)b * NOSC + j];
        sc += R[M_TOT + (size_t)b * NOSC + j];
    }
    for (int off = 32; off > 0; off >>= 1) {
        ss += __shfl_down(ss, off);
        sc += __shfl_down(sc, off);
    }
    __shared__ float red[8];
    const int w = t >> 6;
    if ((t & 63) == 0) { red[w * 2] = sc; red[w * 2 + 1] = ss; }
    __syncthreads();
    if (t == 0) {
        float tc = 0.0f, ts = 0.0f;
        for (int k = 0; k < 4; ++k) { tc += red[k * 2]; ts += red[k * 2 + 1]; }
        tc /= (float)NOSC;
        ts /= (float)NOSC;
        coh[b] = sqrtf(tc * tc + ts * ts);
    }
}

// ---------- legacy fallback (round-2 path) for tiny workspaces ----------
template <int SPLIT>
__global__ void couple_part_kernel(const float* __restrict__ Kmat,
                                   const float* __restrict__ Rm,
                                   float* __restrict__ P) {
    constexpr int JT = NOSC / SPLIT;
    const int t = threadIdx.x;
    const int cg = t & 15;
    const int rg = t >> 4;
    const int i = blockIdx.x * 16 + rg;
    const int s = blockIdx.y;
    const int jb = s * JT;

    const float* __restrict__ Krow = Kmat + (size_t)i * NOSC + jb;
    const float* __restrict__ Rs   = Rm + (size_t)cg * NOSC + jb;
    const float* __restrict__ Rc   = Rm + (size_t)(NB + cg) * NOSC + jb;

    float aS = 0.0f, aC = 0.0f;
#pragma unroll 4
    for (int j = 0; j < JT; j += 4) {
        float4 kv = *reinterpret_cast<const float4*>(Krow + j);
        float4 sv = *reinterpret_cast<const float4*>(Rs + j);
        float4 cv = *reinterpret_cast<const float4*>(Rc + j);
        aS = fmaf(kv.x, sv.x, aS); aS = fmaf(kv.y, sv.y, aS);
        aS = fmaf(kv.z, sv.z, aS); aS = fmaf(kv.w, sv.w, aS);
        aC = fmaf(kv.x, cv.x, aC); aC = fmaf(kv.y, cv.y, aC);
        aC = fmaf(kv.z, cv.z, aC); aC = fmaf(kv.w, cv.w, aC);
    }
    const int o = i * NB + cg;
    P[(size_t)s * M_TOT + o] = aS;
    P[(size_t)(SPLIT + s) * M_TOT + o] = aC;
}

__global__ void update_kernel(const float* __restrict__ P, int split,
                              const float* __restrict__ omega,
                              const float* __restrict__ kg,
                              const float* __restrict__ mod,
                              float* __restrict__ th,
                              float* __restrict__ R) {
    const int o = blockIdx.x * blockDim.x + threadIdx.x;  // o = i*16 + b
    if (o >= M_TOT) return;
    const int i = o >> 4;
    const int b = o & 15;

    float aS = 0.0f, aC = 0.0f;
    for (int s = 0; s < split; ++s) {
        aS += P[(size_t)s * M_TOT + o];
        aC += P[(size_t)(split + s) * M_TOT + o];
    }

    const size_t ti = (size_t)b * NOSC + i;
    const float sin_i = R[ti];
    const float cos_i = R[M_TOT + ti];
    const float scale = kg[0] * (1.0f + mod[0]) * (1.0f / (float)NOSC);
    const float coupling = cos_i * aS - sin_i * aC;

    float nt = th[ti] + DT * (omega[i] + scale * coupling);
    float ws, wc;
    sincosf(nt, &ws, &wc);
    th[ti] = atan2f(ws, wc);
    R[ti] = ws;
    R[M_TOT + ti] = wc;
}

extern "C" void kernel_launch(void* const* d_in, const int* in_sizes, int n_in,
                              void* d_out, int out_size, void* d_ws, size_t ws_size,
                              hipStream_t stream) {
    const float* theta_in = (const float*)d_in[0];
    const float* Kmat     = (const float*)d_in[1];
    const float* omega    = (const float*)d_in[2];
    const float* kg       = (const float*)d_in[3];
    const float* mod      = (const float*)d_in[4];

    float* th  = (float*)d_out;               // [NB][NOSC] final theta
    float* coh = (float*)d_out + M_TOT;       // [NB]
    float* R   = (float*)d_ws;                // [2*M_TOT] sin/cos
    float* P   = (float*)d_ws + 2 * M_TOT;    // partials

    const size_t r_bytes = (size_t)2 * M_TOT * sizeof(float);
    const size_t p_new   = (size_t)32 * NSPLIT * NOSC * sizeof(float);  // 8 MB

    init_kernel<<<(M_TOT + 255) / 256, 256, 0, stream>>>(theta_in, th, R);

    if (ws_size >= r_bytes + p_new) {
        for (int s = 0; s < 10; ++s) {
            gemm_kernel<<<dim3(NSPLIT, 16), 256, 0, stream>>>(Kmat, R, P);
            if (s < 9)
                update2_kernel<false><<<M_TOT / 64, 64, 0, stream>>>(P, omega, kg, mod, th, R);
            else
                update2_kernel<true><<<M_TOT / 64, 64, 0, stream>>>(P, omega, kg, mod, th, R);
        }
    } else {
        // legacy round-2 path for small workspaces
        int split = 0;
        auto p_bytes = [](int sp) { return (size_t)2 * sp * M_TOT * sizeof(float); };
        if (ws_size >= r_bytes + p_bytes(8)) split = 8;
        else if (ws_size >= r_bytes + p_bytes(4)) split = 4;
        else if (ws_size >= r_bytes + p_bytes(2)) split = 2;
        else split = 1;
        for (int s = 0; s < 10; ++s) {
            dim3 grid(NOSC / 16, split);
            if (split == 8)      couple_part_kernel<8><<<grid, 256, 0, stream>>>(Kmat, R, P);
            else if (split == 4) couple_part_kernel<4><<<grid, 256, 0, stream>>>(Kmat, R, P);
            else if (split == 2) couple_part_kernel<2><<<grid, 256, 0, stream>>>(Kmat, R, P);
            else                 couple_part_kernel<1><<<grid, 256, 0, stream>>>(Kmat, R, P);
            update_kernel<<<(M_TOT + 255) / 256, 256, 0, stream>>>(P, split, omega, kg, mod, th, R);
        }
    }

    coherence_kernel<<<NB, 256, 0, stream>>>(R, coh);
}